// Round 10
// baseline (222.192 us; speedup 1.0000x reference)
//
#include <hip/hip_runtime.h>
#include <stdint.h>
#include <stddef.h>

#define CDIM 1024
#define HWD  1024   // 32*32
#define TD   16
#define BD   2
#define NH   16
#define DHD  64

typedef __attribute__((ext_vector_type(8))) short bf16x8;
typedef __attribute__((ext_vector_type(4))) short bf16x4;
typedef __attribute__((ext_vector_type(4))) float f32x4;

static __device__ __forceinline__ short f2bf(float f) {
  uint32_t u = __builtin_bit_cast(uint32_t, f);
  uint32_t r = (u + 0x7FFFu + ((u >> 16) & 1u)) >> 16;
  return (short)(uint16_t)r;
}
static __device__ __forceinline__ float bf2f(short s) {
  return __builtin_bit_cast(float, (uint32_t)((uint16_t)s) << 16);
}

static __device__ __forceinline__ void gl_lds16(const short* g, short* l) {
  __builtin_amdgcn_global_load_lds((const __attribute__((address_space(1))) unsigned int*)g,
                                   (__attribute__((address_space(3))) unsigned int*)l,
                                   16, 0, 0);
}

// ---------------- K0: cast Wq|Wk|Wv -> bf16 (fused, one launch) ----------------
__global__ void k_cast3(const float* __restrict__ Wq, const float* __restrict__ Wk,
                        const float* __restrict__ Wv, short* __restrict__ Wqkb,
                        short* __restrict__ Wb) {
  int bid = blockIdx.x;                         // 0..3071
  int mat = bid >> 10;                          // 0:Wq 1:Wk 2:Wv
  const float* src = mat == 0 ? Wq : (mat == 1 ? Wk : Wv);
  short* dst = mat == 0 ? Wqkb : (mat == 1 ? Wqkb + 1048576 : Wb);
  int i = ((bid & 1023) * 256 + threadIdx.x) * 4;
  f32x4 v = *(const f32x4*)&src[i];
  dst[i + 0] = f2bf(v[0]);
  dst[i + 1] = f2bf(v[1]);
  dst[i + 2] = f2bf(v[2]);
  dst[i + 3] = f2bf(v[3]);
}

// ---------------- K1: LayerNorm v3 — occupancy/burst-optimized single kernel ----
// grid (16 px-groups of 64, 32 bt), block 512. Thread = (pq 0..15 [4 px], cr 0..31).
// Pass A: pure stats burst (32 independent f32x4 loads, no value retention).
// Pass B: re-read x (L2/L3-resident), normalize, swizzled LDS transpose in 8
// c-chunks of 128, contiguous xnT writes; pool partials via 16-lane shfl_xor.
// LDS ~17 KB (stats buffers aliased onto transpose tile) -> no LDS occupancy cap.
__global__ __launch_bounds__(512) void k_ln(const float* __restrict__ x,
                                            const float* __restrict__ lnw,
                                            const float* __restrict__ lnb,
                                            short* __restrict__ xnT,
                                            float* __restrict__ part) {
  int bt = blockIdx.y;
  int pg = blockIdx.x;
  int P0 = pg * 64;
  int tid = threadIdx.x;
  int pq = tid & 15, cr = tid >> 4;             // px-quad (4 px), c-row group 0..31
  int pbase = P0 + pq * 4;
  const float* xs = x + (size_t)bt * CDIM * HWD;
  short* outB = xnT + (size_t)bt * CDIM * HWD;

  __shared__ __align__(16) char lbuf[2 * 32 * 65 * 4];  // 16.6 KB: stats | tile alias
  float* redA = (float*)lbuf;                    // [32][65]
  float* redB = redA + 32 * 65;                  // [32][65]
  short* tile = (short*)lbuf;                    // [64][130] (pass B)
  __shared__ float muS[64], rsS[64];

  // ---- pass A: per-pixel sum/sumsq over C, 32-deep independent load burst
  float s[4] = {}, s2[4] = {};
  #pragma unroll
  for (int j = 0; j < 32; ++j) {
    int c = cr + 32 * j;
    f32x4 v = *(const f32x4*)&xs[(size_t)c * HWD + pbase];
    #pragma unroll
    for (int i = 0; i < 4; ++i) { s[i] += v[i]; s2[i] += v[i] * v[i]; }
  }
  #pragma unroll
  for (int i = 0; i < 4; ++i) {
    redA[cr * 65 + pq * 4 + i] = s[i];
    redB[cr * 65 + pq * 4 + i] = s2[i];
  }
  __syncthreads();
  if (tid < 64) {
    float a = 0.f, b2 = 0.f;
    #pragma unroll
    for (int k = 0; k < 32; ++k) { a += redA[k * 65 + tid]; b2 += redB[k * 65 + tid]; }
    float mu = a * (1.0f / CDIM);
    float var = b2 * (1.0f / CDIM) - mu * mu;
    muS[tid] = mu;
    rsS[tid] = rsqrtf(var + 1e-5f);
  }
  __syncthreads();   // finalize reads of redA/redB done -> tile may reuse lbuf
  float mu_[4], rs_[4];
  #pragma unroll
  for (int i = 0; i < 4; ++i) { mu_[i] = muS[pq * 4 + i]; rs_[i] = rsS[pq * 4 + i]; }

  // ---- pass B: 8 chunks of 128 c
  for (int h = 0; h < 8; ++h) {
    #pragma unroll
    for (int jj = 0; jj < 4; ++jj) {
      int cl = cr + 32 * jj;                    // 0..127
      int c = h * 128 + cl;
      f32x4 v = *(const f32x4*)&xs[(size_t)c * HWD + pbase];
      float w = lnw[c], bb = lnb[c];
      int cc = cl >> 3, c7 = cl & 7;
      float psum = 0.f;
      #pragma unroll
      for (int i = 0; i < 4; ++i) {
        int px = pq * 4 + i;
        float xn = (v[i] - mu_[i]) * rs_[i] * w + bb;
        psum += xn;
        tile[px * 130 + ((cc ^ (px & 7)) << 3) + c7] = f2bf(xn);
      }
      // pool partial: reduce over the 16 pq lanes (same wave, xor within group)
      psum += __shfl_xor(psum, 1, 64);
      psum += __shfl_xor(psum, 2, 64);
      psum += __shfl_xor(psum, 4, 64);
      psum += __shfl_xor(psum, 8, 64);
      if (pq == 0)
        part[((size_t)(bt * 16 + pg)) * CDIM + c] = psum;
    }
    __syncthreads();
    // transposed write: thread = (qr 0..63, sg 0..7), 16 consecutive c = 32 B
    {
      int qr = tid & 63, sg = tid >> 6;
      int q = (qr & 31) * 32 + pg * 2 + (qr >> 5);   // spatial transpose
      short* dst = outB + (size_t)q * CDIM + h * 128 + sg * 16;
      #pragma unroll
      for (int mm = 0; mm < 2; ++mm) {
        int cc = sg * 2 + mm;
        bf16x8 vv = *(const bf16x8*)&tile[qr * 130 + ((cc ^ (qr & 7)) << 3)];
        *(bf16x8*)&dst[mm * 8] = vv;
      }
    }
    __syncthreads();
  }
}

// ---------------- K2: pooled(bf16) = mean over pixels (reduce 16 partials) ------
__global__ void k_pool_red(const float* __restrict__ part, short* __restrict__ pooledb) {
  int bt = blockIdx.y;
  int c = blockIdx.x * 256 + threadIdx.x;
  float s = 0.f;
  #pragma unroll
  for (int pc = 0; pc < 16; ++pc) s += part[((size_t)(bt * 16 + pc)) * CDIM + c];
  pooledb[bt * CDIM + c] = f2bf(s * (1.0f / HWD));
}

// ---------------- K3: q|k = pooled @ [Wq;Wk]^T via MFMA ----------------
__global__ __launch_bounds__(256) void k_qk_mfma(const short* __restrict__ Wqkb,
                                                 const short* __restrict__ pooledb,
                                                 float* __restrict__ qm,
                                                 float* __restrict__ km) {
  int n0 = blockIdx.x * 128;
  __shared__ __align__(16) short lA[32 * 32];
  __shared__ __align__(16) short lB[128 * 32];
  int tid = threadIdx.x, lane = tid & 63, wid = tid >> 6;
  int s0 = wid * 128 + lane, s1 = s0 + 64;
  int fr = lane & 15, fk = (lane >> 4) * 8;
  f32x4 acc[2][2] = {};

  for (int kt = 0; kt < CDIM / 32; ++kt) {
    int k0 = kt * 32;
    __syncthreads();
    gl_lds16(&Wqkb[(size_t)(n0 + (s0 >> 2)) * CDIM + k0 + (s0 & 3) * 8], &lB[s0 * 8]);
    gl_lds16(&Wqkb[(size_t)(n0 + (s1 >> 2)) * CDIM + k0 + (s1 & 3) * 8], &lB[s1 * 8]);
    if (wid < 2) {
      gl_lds16(&pooledb[(size_t)(tid >> 2) * CDIM + k0 + (tid & 3) * 8], &lA[tid * 8]);
    }
    __syncthreads();
    bf16x8 af[2], bfr[2];
    #pragma unroll
    for (int mi = 0; mi < 2; ++mi)
      af[mi] = *(const bf16x8*)&lA[(mi * 16 + fr) * 32 + fk];
    #pragma unroll
    for (int ni = 0; ni < 2; ++ni)
      bfr[ni] = *(const bf16x8*)&lB[(wid * 32 + ni * 16 + fr) * 32 + fk];
    #pragma unroll
    for (int mi = 0; mi < 2; ++mi)
      #pragma unroll
      for (int ni = 0; ni < 2; ++ni)
        acc[mi][ni] = __builtin_amdgcn_mfma_f32_16x16x32_bf16(af[mi], bfr[ni], acc[mi][ni], 0, 0, 0);
  }

  int cr = lane >> 4;
  #pragma unroll
  for (int mi = 0; mi < 2; ++mi)
    #pragma unroll
    for (int ni = 0; ni < 2; ++ni)
      #pragma unroll
      for (int rr = 0; rr < 4; ++rr) {
        int row = mi * 16 + cr * 4 + rr;
        int col = n0 + wid * 32 + ni * 16 + fr;
        float v = acc[mi][ni][rr];
        if (col < 1024) qm[(size_t)row * CDIM + col] = v;
        else            km[(size_t)row * CDIM + col - 1024] = v;
      }
}

// ---------------- K4: attention softmax ----------------
__global__ void k_attn(const float* __restrict__ qm, const float* __restrict__ km,
                       float* __restrict__ attn) {
  int bg = blockIdx.x;
  int b = bg >> 4, g = bg & 15;
  int s = threadIdx.x >> 4, t = threadIdx.x & 15;
  const float* qr = qm + (size_t)(b * TD + s) * CDIM + g * DHD;
  const float* kr = km + (size_t)(b * TD + t) * CDIM + g * DHD;
  float d = 0.f;
  #pragma unroll
  for (int i = 0; i < DHD; ++i) d += qr[i] * kr[i];
  d *= 0.125f;
  float m = d;
  #pragma unroll
  for (int off = 8; off; off >>= 1) m = fmaxf(m, __shfl_xor(m, off, 16));
  float e = __expf(d - m);
  float sum = e;
  #pragma unroll
  for (int off = 8; off; off >>= 1) sum += __shfl_xor(sum, off, 16);
  attn[(size_t)bg * 256 + s * 16 + t] = e / sum;
}

// ---------------- K5: V-GEMM — R4-v2, UNTOUCHED (best measured) ----------------
__global__ __launch_bounds__(512, 2) void k_vgemm(const short* __restrict__ Wb,
                                                  const short* __restrict__ xnT,
                                                  short* __restrict__ vp) {
  int bid = blockIdx.x;
  int swz = (bid & 7) * 64 + (bid >> 3);   // bijective XCD swizzle (512%8==0)
  int bt = swz >> 4;
  int m0 = ((swz >> 2) & 3) * 256;
  int n0 = (swz & 3) * 256;
  const short* Bm = xnT + (size_t)bt * CDIM * HWD;

  __shared__ __align__(16) short lA[2][256 * 64];   // 2 x 32 KB
  __shared__ __align__(16) short lB[2][256 * 64];   // 2 x 32 KB

  int tid = threadIdx.x, lane = tid & 63, wid = tid >> 6;
  int wm = wid >> 2, wn = wid & 3;   // wave tile: 128(M) x 64(N)

  int srow = wid * 8 + (lane >> 3);
  int schunk = (lane & 7) ^ (lane >> 3);
  const short* gA = Wb + (size_t)(m0 + srow) * CDIM + schunk * 8;
  const short* gB = Bm + (size_t)(n0 + srow) * CDIM + schunk * 8;
  int doff = wid * 512 + lane * 8;

  int fr = lane & 15, klane = lane >> 4;
  int c0 = ((klane ^ (fr & 7)) * 8);
  int rA = (wm * 128 + fr) * 64;
  int rB = (wn * 64 + fr) * 64;

  f32x4 acc[8][4] = {};
  bf16x8 bq[4], af[4];

#define ISSUE(p, kt1, nb)                                                      \
  do {                                                                         \
    gl_lds16(gA + (size_t)(p) * 64 * CDIM + (kt1) * 64, &lA[nb][(p) * 4096 + doff]); \
    gl_lds16(gB + (size_t)(p) * 64 * CDIM + (kt1) * 64, &lB[nb][(p) * 4096 + doff]); \
  } while (0)
#define RDA(mi, ks, b) (*(const bf16x8*)&lA[b][rA + (mi) * 1024 + (c0 ^ ((ks) * 32))])
#define RDB(ni, ks, b) (*(const bf16x8*)&lB[b][rB + (ni) * 1024 + (c0 ^ ((ks) * 32))])

  // prologue: stage tile 0 into buf 0
  ISSUE(0, 0, 0); ISSUE(1, 0, 0); ISSUE(2, 0, 0); ISSUE(3, 0, 0);

  for (int kt = 0; kt < 16; ++kt) {
    int cur = kt & 1, nxt = cur ^ 1;
    bool st = (kt + 1 < 16);
    // ---- phase 0: quad (mh=0, ks=0); rendezvous on tile kt staging
    if (st) {
      ISSUE(0, kt + 1, nxt);
      asm volatile("s_waitcnt vmcnt(2)" ::: "memory");
    } else {
      asm volatile("s_waitcnt vmcnt(0)" ::: "memory");
    }
    __builtin_amdgcn_s_barrier();
    #pragma unroll
    for (int ni = 0; ni < 4; ++ni) bq[ni] = RDB(ni, 0, cur);
    #pragma unroll
    for (int mi = 0; mi < 4; ++mi) af[mi] = RDA(mi, 0, cur);
    __builtin_amdgcn_s_setprio(1);
    #pragma unroll
    for (int mi = 0; mi < 4; ++mi)
      #pragma unroll
      for (int ni = 0; ni < 4; ++ni)
        acc[mi][ni] = __builtin_amdgcn_mfma_f32_16x16x32_bf16(af[mi], bq[ni], acc[mi][ni], 0, 0, 0);
    __builtin_amdgcn_s_setprio(0);
    __builtin_amdgcn_s_barrier();
    // ---- phase 1: quad (mh=1, ks=0)
    #pragma unroll
    for (int mi = 0; mi < 4; ++mi) af[mi] = RDA(4 + mi, 0, cur);
    if (st) ISSUE(1, kt + 1, nxt);
    __builtin_amdgcn_s_barrier();
    __builtin_amdgcn_s_setprio(1);
    #pragma unroll
    for (int mi = 0; mi < 4; ++mi)
      #pragma unroll
      for (int ni = 0; ni < 4; ++ni)
        acc[4 + mi][ni] = __builtin_amdgcn_mfma_f32_16x16x32_bf16(af[mi], bq[ni], acc[4 + mi][ni], 0, 0, 0);
    __builtin_amdgcn_s_setprio(0);
    __builtin_amdgcn_s_barrier();
    // ---- phase 2: quad (mh=0, ks=1)
    #pragma unroll
    for (int ni = 0; ni < 4; ++ni) bq[ni] = RDB(ni, 1, cur);
    #pragma unroll
    for (int mi = 0; mi < 4; ++mi) af[mi] = RDA(mi, 1, cur);
    if (st) ISSUE(2, kt + 1, nxt);
    __builtin_amdgcn_s_barrier();
    __builtin_amdgcn_s_setprio(1);
    #pragma unroll
    for (int mi = 0; mi < 4; ++mi)
      #pragma unroll
      for (int ni = 0; ni < 4; ++ni)
        acc[mi][ni] = __builtin_amdgcn_mfma_f32_16x16x32_bf16(af[mi], bq[ni], acc[mi][ni], 0, 0, 0);
    __builtin_amdgcn_s_setprio(0);
    __builtin_amdgcn_s_barrier();
    // ---- phase 3: quad (mh=1, ks=1)
    #pragma unroll
    for (int mi = 0; mi < 4; ++mi) af[mi] = RDA(4 + mi, 1, cur);
    if (st) ISSUE(3, kt + 1, nxt);
    __builtin_amdgcn_s_barrier();
    __builtin_amdgcn_s_setprio(1);
    #pragma unroll
    for (int mi = 0; mi < 4; ++mi)
      #pragma unroll
      for (int ni = 0; ni < 4; ++ni)
        acc[4 + mi][ni] = __builtin_amdgcn_mfma_f32_16x16x32_bf16(af[mi], bq[ni], acc[4 + mi][ni], 0, 0, 0);
    __builtin_amdgcn_s_setprio(0);
    __builtin_amdgcn_s_barrier();
  }
#undef ISSUE
#undef RDA
#undef RDB

  short* outB = vp + (size_t)bt * CDIM * HWD;
  int cr = lane >> 4;
  #pragma unroll
  for (int mi = 0; mi < 8; ++mi)
    #pragma unroll
    for (int ni = 0; ni < 4; ++ni)
      #pragma unroll
      for (int r = 0; r < 4; ++r) {
        int row = m0 + wm * 128 + mi * 16 + cr * 4 + r;   // c
        int col = n0 + wn * 64 + ni * 16 + fr;            // q
        outB[(size_t)row * HWD + col] = f2bf(acc[mi][ni][r]);
      }
}

// ---------------- K6: T-mix ----------------
__global__ __launch_bounds__(256) void k_mix(const short* __restrict__ vp,
                                             const float* __restrict__ attn,
                                             float* __restrict__ out) {
  int c = blockIdx.x;
  int b = blockIdx.y;
  int g = c >> 6;
  __shared__ __align__(16) short vpl[TD * HWD];  // 32 KB
  __shared__ float at[256];
  int tid = threadIdx.x;
  at[tid] = attn[(size_t)(b * NH + g) * 256 + tid];
  #pragma unroll
  for (int j = 0; j < 8; ++j) {
    int chunk = j * 256 + tid;
    int t = chunk >> 7, qc = chunk & 127;
    bf16x8 v = *(const bf16x8*)&vp[((size_t)(b * TD + t) * CDIM + c) * HWD + qc * 8];
    *(bf16x8*)&vpl[t * HWD + qc * 8] = v;
  }
  __syncthreads();
  int p = tid * 4;
  #pragma unroll
  for (int sh = 0; sh < 2; ++sh) {
    f32x4 acc[8] = {};
    #pragma unroll
    for (int t = 0; t < TD; ++t) {
      bf16x4 v4 = *(const bf16x4*)&vpl[t * HWD + p];
      f32x4 vf = {bf2f(v4[0]), bf2f(v4[1]), bf2f(v4[2]), bf2f(v4[3])};
      #pragma unroll
      for (int s8 = 0; s8 < 8; ++s8) {
        float a = at[(sh * 8 + s8) * 16 + t];
        acc[s8] += a * vf;
      }
    }
    #pragma unroll
    for (int s8 = 0; s8 < 8; ++s8) {
      int s = sh * 8 + s8;
      *(f32x4*)&out[((size_t)(b * TD + s) * CDIM + c) * HWD + p] = acc[s8];
    }
  }
}

// ---------------- launch ----------------
extern "C" void kernel_launch(void* const* d_in, const int* in_sizes, int n_in,
                              void* d_out, int out_size, void* d_ws, size_t ws_size,
                              hipStream_t stream) {
  const float* x   = (const float*)d_in[0];
  const float* lnw = (const float*)d_in[1];
  const float* lnb = (const float*)d_in[2];
  const float* Wq  = (const float*)d_in[3];
  const float* Wk  = (const float*)d_in[4];
  const float* Wv  = (const float*)d_in[5];
  float* out = (float*)d_out;

  char* ws = (char*)d_ws;
  const size_t XNT_OFF   = 0;                       // bf16 [32][1024 q][1024 c]  64 MiB
  const size_t VP_OFF    = XNT_OFF + 67108864;      // bf16 [32][1024 c][1024 q]  64 MiB
  const size_t WB_OFF    = VP_OFF + 67108864;       // bf16 Wv                    2 MiB
  const size_t WQKB_OFF  = WB_OFF + 2097152;        // bf16 [Wq;Wk]               4 MiB
  const size_t POOLB_OFF = WQKB_OFF + 4194304;      // bf16 [32][1024]
  const size_t QM_OFF    = POOLB_OFF + 65536;
  const size_t KM_OFF    = QM_OFF + 131072;
  const size_t ATTN_OFF  = KM_OFF + 131072;         // f32 [32][16][16]

  short* xnT    = (short*)(ws + XNT_OFF);
  short* vp     = (short*)(ws + VP_OFF);
  // pool partials alias the vp region: written by k_ln, consumed by k_pool_red,
  // both strictly before k_vgemm writes vp (stream-ordered).
  float* part   = (float*)(ws + VP_OFF);            // f32 [32][16][1024] = 2 MiB
  short* Wb     = (short*)(ws + WB_OFF);
  short* Wqkb   = (short*)(ws + WQKB_OFF);
  short* poolb  = (short*)(ws + POOLB_OFF);
  float* qm     = (float*)(ws + QM_OFF);
  float* km     = (float*)(ws + KM_OFF);
  float* attn   = (float*)(ws + ATTN_OFF);

  k_cast3<<<dim3(3072), 256, 0, stream>>>(Wq, Wk, Wv, Wqkb, Wb);
  k_ln<<<dim3(16, 32), 512, 0, stream>>>(x, lnw, lnb, xnT, part);
  k_pool_red<<<dim3(4, 32), 256, 0, stream>>>(part, poolb);
  k_qk_mfma<<<dim3(16), 256, 0, stream>>>(Wqkb, poolb, qm, km);
  k_attn<<<dim3(32), 256, 0, stream>>>(qm, km, attn);
  k_vgemm<<<dim3(512), 512, 0, stream>>>(Wb, xnT, vp);
  k_mix<<<dim3(1024, 2), 256, 0, stream>>>(vp, attn, out);
}

// Round 11
// 209.767 us; speedup vs baseline: 1.0592x; 1.0592x over previous
//
#include <hip/hip_runtime.h>
#include <stdint.h>
#include <stddef.h>

#define CDIM 1024
#define HWD  1024   // 32*32
#define TD   16
#define BD   2
#define NH   16
#define DHD  64

typedef __attribute__((ext_vector_type(8))) short bf16x8;
typedef __attribute__((ext_vector_type(4))) short bf16x4;
typedef __attribute__((ext_vector_type(4))) float f32x4;

static __device__ __forceinline__ short f2bf(float f) {
  uint32_t u = __builtin_bit_cast(uint32_t, f);
  uint32_t r = (u + 0x7FFFu + ((u >> 16) & 1u)) >> 16;
  return (short)(uint16_t)r;
}
static __device__ __forceinline__ float bf2f(short s) {
  return __builtin_bit_cast(float, (uint32_t)((uint16_t)s) << 16);
}

static __device__ __forceinline__ void gl_lds16(const short* g, short* l) {
  __builtin_amdgcn_global_load_lds((const __attribute__((address_space(1))) unsigned int*)g,
                                   (__attribute__((address_space(3))) unsigned int*)l,
                                   16, 0, 0);
}

// ---------------- K0: cast Wq|Wk|Wv -> bf16 (fused, one launch) ----------------
__global__ void k_cast3(const float* __restrict__ Wq, const float* __restrict__ Wk,
                        const float* __restrict__ Wv, short* __restrict__ Wqkb,
                        short* __restrict__ Wb) {
  int bid = blockIdx.x;                         // 0..3071
  int mat = bid >> 10;                          // 0:Wq 1:Wk 2:Wv
  const float* src = mat == 0 ? Wq : (mat == 1 ? Wk : Wv);
  short* dst = mat == 0 ? Wqkb : (mat == 1 ? Wqkb + 1048576 : Wb);
  int i = ((bid & 1023) * 256 + threadIdx.x) * 4;
  f32x4 v = *(const f32x4*)&src[i];
  dst[i + 0] = f2bf(v[0]);
  dst[i + 1] = f2bf(v[1]);
  dst[i + 2] = f2bf(v[2]);
  dst[i + 3] = f2bf(v[3]);
}

// ---------------- K1: LayerNorm v3 (kept from R10 — measured good) --------------
__global__ __launch_bounds__(512) void k_ln(const float* __restrict__ x,
                                            const float* __restrict__ lnw,
                                            const float* __restrict__ lnb,
                                            short* __restrict__ xnT,
                                            float* __restrict__ part) {
  int bt = blockIdx.y;
  int pg = blockIdx.x;
  int P0 = pg * 64;
  int tid = threadIdx.x;
  int pq = tid & 15, cr = tid >> 4;             // px-quad (4 px), c-row group 0..31
  int pbase = P0 + pq * 4;
  const float* xs = x + (size_t)bt * CDIM * HWD;
  short* outB = xnT + (size_t)bt * CDIM * HWD;

  __shared__ __align__(16) char lbuf[2 * 32 * 65 * 4];  // 16.6 KB: stats | tile alias
  float* redA = (float*)lbuf;                    // [32][65]
  float* redB = redA + 32 * 65;                  // [32][65]
  short* tile = (short*)lbuf;                    // [64][130] (pass B)
  __shared__ float muS[64], rsS[64];

  // ---- pass A: per-pixel sum/sumsq over C, 32-deep independent load burst
  float s[4] = {}, s2[4] = {};
  #pragma unroll
  for (int j = 0; j < 32; ++j) {
    int c = cr + 32 * j;
    f32x4 v = *(const f32x4*)&xs[(size_t)c * HWD + pbase];
    #pragma unroll
    for (int i = 0; i < 4; ++i) { s[i] += v[i]; s2[i] += v[i] * v[i]; }
  }
  #pragma unroll
  for (int i = 0; i < 4; ++i) {
    redA[cr * 65 + pq * 4 + i] = s[i];
    redB[cr * 65 + pq * 4 + i] = s2[i];
  }
  __syncthreads();
  if (tid < 64) {
    float a = 0.f, b2 = 0.f;
    #pragma unroll
    for (int k = 0; k < 32; ++k) { a += redA[k * 65 + tid]; b2 += redB[k * 65 + tid]; }
    float mu = a * (1.0f / CDIM);
    float var = b2 * (1.0f / CDIM) - mu * mu;
    muS[tid] = mu;
    rsS[tid] = rsqrtf(var + 1e-5f);
  }
  __syncthreads();   // finalize reads of redA/redB done -> tile may reuse lbuf
  float mu_[4], rs_[4];
  #pragma unroll
  for (int i = 0; i < 4; ++i) { mu_[i] = muS[pq * 4 + i]; rs_[i] = rsS[pq * 4 + i]; }

  // ---- pass B: 8 chunks of 128 c
  for (int h = 0; h < 8; ++h) {
    #pragma unroll
    for (int jj = 0; jj < 4; ++jj) {
      int cl = cr + 32 * jj;                    // 0..127
      int c = h * 128 + cl;
      f32x4 v = *(const f32x4*)&xs[(size_t)c * HWD + pbase];
      float w = lnw[c], bb = lnb[c];
      int cc = cl >> 3, c7 = cl & 7;
      float psum = 0.f;
      #pragma unroll
      for (int i = 0; i < 4; ++i) {
        int px = pq * 4 + i;
        float xn = (v[i] - mu_[i]) * rs_[i] * w + bb;
        psum += xn;
        tile[px * 130 + ((cc ^ (px & 7)) << 3) + c7] = f2bf(xn);
      }
      // pool partial: reduce over the 16 pq lanes (same wave, xor within group)
      psum += __shfl_xor(psum, 1, 64);
      psum += __shfl_xor(psum, 2, 64);
      psum += __shfl_xor(psum, 4, 64);
      psum += __shfl_xor(psum, 8, 64);
      if (pq == 0)
        part[((size_t)(bt * 16 + pg)) * CDIM + c] = psum;
    }
    __syncthreads();
    // transposed write: thread = (qr 0..63, sg 0..7), 16 consecutive c = 32 B
    {
      int qr = tid & 63, sg = tid >> 6;
      int q = (qr & 31) * 32 + pg * 2 + (qr >> 5);   // spatial transpose
      short* dst = outB + (size_t)q * CDIM + h * 128 + sg * 16;
      #pragma unroll
      for (int mm = 0; mm < 2; ++mm) {
        int cc = sg * 2 + mm;
        bf16x8 vv = *(const bf16x8*)&tile[qr * 130 + ((cc ^ (qr & 7)) << 3)];
        *(bf16x8*)&dst[mm * 8] = vv;
      }
    }
    __syncthreads();
  }
}

// ---------------- K2: pooled(bf16) = mean over pixels (reduce 16 partials) ------
__global__ void k_pool_red(const float* __restrict__ part, short* __restrict__ pooledb) {
  int bt = blockIdx.y;
  int c = blockIdx.x * 256 + threadIdx.x;
  float s = 0.f;
  #pragma unroll
  for (int pc = 0; pc < 16; ++pc) s += part[((size_t)(bt * 16 + pc)) * CDIM + c];
  pooledb[bt * CDIM + c] = f2bf(s * (1.0f / HWD));
}

// ---------------- K3: q|k = pooled @ [Wq;Wk]^T via MFMA ----------------
__global__ __launch_bounds__(256) void k_qk_mfma(const short* __restrict__ Wqkb,
                                                 const short* __restrict__ pooledb,
                                                 float* __restrict__ qm,
                                                 float* __restrict__ km) {
  int n0 = blockIdx.x * 128;
  __shared__ __align__(16) short lA[32 * 32];
  __shared__ __align__(16) short lB[128 * 32];
  int tid = threadIdx.x, lane = tid & 63, wid = tid >> 6;
  int s0 = wid * 128 + lane, s1 = s0 + 64;
  int fr = lane & 15, fk = (lane >> 4) * 8;
  f32x4 acc[2][2] = {};

  for (int kt = 0; kt < CDIM / 32; ++kt) {
    int k0 = kt * 32;
    __syncthreads();
    gl_lds16(&Wqkb[(size_t)(n0 + (s0 >> 2)) * CDIM + k0 + (s0 & 3) * 8], &lB[s0 * 8]);
    gl_lds16(&Wqkb[(size_t)(n0 + (s1 >> 2)) * CDIM + k0 + (s1 & 3) * 8], &lB[s1 * 8]);
    if (wid < 2) {
      gl_lds16(&pooledb[(size_t)(tid >> 2) * CDIM + k0 + (tid & 3) * 8], &lA[tid * 8]);
    }
    __syncthreads();
    bf16x8 af[2], bfr[2];
    #pragma unroll
    for (int mi = 0; mi < 2; ++mi)
      af[mi] = *(const bf16x8*)&lA[(mi * 16 + fr) * 32 + fk];
    #pragma unroll
    for (int ni = 0; ni < 2; ++ni)
      bfr[ni] = *(const bf16x8*)&lB[(wid * 32 + ni * 16 + fr) * 32 + fk];
    #pragma unroll
    for (int mi = 0; mi < 2; ++mi)
      #pragma unroll
      for (int ni = 0; ni < 2; ++ni)
        acc[mi][ni] = __builtin_amdgcn_mfma_f32_16x16x32_bf16(af[mi], bfr[ni], acc[mi][ni], 0, 0, 0);
  }

  int cr = lane >> 4;
  #pragma unroll
  for (int mi = 0; mi < 2; ++mi)
    #pragma unroll
    for (int ni = 0; ni < 2; ++ni)
      #pragma unroll
      for (int rr = 0; rr < 4; ++rr) {
        int row = mi * 16 + cr * 4 + rr;
        int col = n0 + wid * 32 + ni * 16 + fr;
        float v = acc[mi][ni][rr];
        if (col < 1024) qm[(size_t)row * CDIM + col] = v;
        else            km[(size_t)row * CDIM + col - 1024] = v;
      }
}

// ---------------- K4: attention softmax ----------------
__global__ void k_attn(const float* __restrict__ qm, const float* __restrict__ km,
                       float* __restrict__ attn) {
  int bg = blockIdx.x;
  int b = bg >> 4, g = bg & 15;
  int s = threadIdx.x >> 4, t = threadIdx.x & 15;
  const float* qr = qm + (size_t)(b * TD + s) * CDIM + g * DHD;
  const float* kr = km + (size_t)(b * TD + t) * CDIM + g * DHD;
  float d = 0.f;
  #pragma unroll
  for (int i = 0; i < DHD; ++i) d += qr[i] * kr[i];
  d *= 0.125f;
  float m = d;
  #pragma unroll
  for (int off = 8; off; off >>= 1) m = fmaxf(m, __shfl_xor(m, off, 16));
  float e = __expf(d - m);
  float sum = e;
  #pragma unroll
  for (int off = 8; off; off >>= 1) sum += __shfl_xor(sum, off, 16);
  attn[(size_t)bg * 256 + s * 16 + t] = e / sum;
}

// ---------------- K5: V-GEMM — R3's m97 128² structure + phase-conflict-free ----
// XOR swizzle (address-only change; sync structure untouched).
// vp[bt][c][q] = sum_c' Wv[c,c'] * xnT[bt][q][c']
// 128x128 tile, BK=32, 4 waves, ~7 blocks/CU (implicit cross-block overlap).
// Swizzle: physical chunk p of row r holds logical chunk p^((r>>1)&3); applied
// on the pre-swizzled GLOBAL source (linear LDS dest, rule #21) and on ds_read.
// Per-8-lane-phase bank-group analysis: 8 distinct groups -> conflict-free
// (R3 unswizzled: 2 groups/phase -> 4-way -> the measured 8.4M conflicts).
__global__ __launch_bounds__(256) void k_vgemm(const short* __restrict__ Wb,
                                               const short* __restrict__ xnT,
                                               short* __restrict__ vp) {
  int bt = blockIdx.z;
  int m0 = blockIdx.y * 128;   // output channel c
  int n0 = blockIdx.x * 128;   // pixel q
  const short* A = Wb;                                   // [C][C] k-contig
  const short* Bm = xnT + (size_t)bt * CDIM * HWD;       // [q][c'] k-contig
  __shared__ __align__(16) short lA[128 * 32];
  __shared__ __align__(16) short lB[128 * 32];
  int tid = threadIdx.x;
  int lane = tid & 63;
  int wid = tid >> 6;
  int wr = (wid >> 1) * 64;
  int wc = (wid & 1) * 64;
  f32x4 acc[4][4] = {};

  // staging: row = tid>>2 (and +64), physical chunk = tid&3, source fetches
  // logical chunk (tid&3)^((row>>1)&3) = (tid&3)^((tid>>3)&3)
  int sm = tid >> 2;
  int slc = ((tid & 3) ^ ((tid >> 3) & 3)) * 8;
  const short* gA = A + (size_t)(m0 + sm) * CDIM + slc;
  const short* gB = Bm + (size_t)(n0 + sm) * CDIM + slc;
  short* dA = &lA[tid * 8];
  short* dB = &lB[tid * 8];
  // fragment read: logical chunk klane of row (..+fr) -> physical klane^((fr>>1)&3)
  int fr = lane & 15;
  int c0 = (((lane >> 4) ^ ((fr >> 1) & 3)) * 8);

  for (int kt = 0; kt < CDIM / 32; ++kt) {
    __syncthreads();
    gl_lds16(gA + kt * 32, dA);
    gl_lds16(gA + kt * 32 + (size_t)64 * CDIM, dA + 64 * 32);
    gl_lds16(gB + kt * 32, dB);
    gl_lds16(gB + kt * 32 + (size_t)64 * CDIM, dB + 64 * 32);
    __syncthreads();
    bf16x8 af[4], bfr[4];
    #pragma unroll
    for (int mi = 0; mi < 4; ++mi)
      af[mi] = *(const bf16x8*)&lA[(wr + mi * 16 + fr) * 32 + c0];
    #pragma unroll
    for (int ni = 0; ni < 4; ++ni)
      bfr[ni] = *(const bf16x8*)&lB[(wc + ni * 16 + fr) * 32 + c0];
    #pragma unroll
    for (int mi = 0; mi < 4; ++mi)
      #pragma unroll
      for (int ni = 0; ni < 4; ++ni)
        acc[mi][ni] = __builtin_amdgcn_mfma_f32_16x16x32_bf16(af[mi], bfr[ni], acc[mi][ni], 0, 0, 0);
  }

  short* outB = vp + (size_t)bt * CDIM * HWD;
  int cr = lane >> 4;
  #pragma unroll
  for (int mi = 0; mi < 4; ++mi)
    #pragma unroll
    for (int ni = 0; ni < 4; ++ni)
      #pragma unroll
      for (int r = 0; r < 4; ++r) {
        int row = m0 + wr + mi * 16 + cr * 4 + r;   // c
        int col = n0 + wc + ni * 16 + fr;           // q
        outB[(size_t)row * HWD + col] = f2bf(acc[mi][ni][r]);
      }
}

// ---------------- K6: T-mix ----------------
__global__ __launch_bounds__(256) void k_mix(const short* __restrict__ vp,
                                             const float* __restrict__ attn,
                                             float* __restrict__ out) {
  int c = blockIdx.x;
  int b = blockIdx.y;
  int g = c >> 6;
  __shared__ __align__(16) short vpl[TD * HWD];  // 32 KB
  __shared__ float at[256];
  int tid = threadIdx.x;
  at[tid] = attn[(size_t)(b * NH + g) * 256 + tid];
  #pragma unroll
  for (int j = 0; j < 8; ++j) {
    int chunk = j * 256 + tid;
    int t = chunk >> 7, qc = chunk & 127;
    bf16x8 v = *(const bf16x8*)&vp[((size_t)(b * TD + t) * CDIM + c) * HWD + qc * 8];
    *(bf16x8*)&vpl[t * HWD + qc * 8] = v;
  }
  __syncthreads();
  int p = tid * 4;
  #pragma unroll
  for (int sh = 0; sh < 2; ++sh) {
    f32x4 acc[8] = {};
    #pragma unroll
    for (int t = 0; t < TD; ++t) {
      bf16x4 v4 = *(const bf16x4*)&vpl[t * HWD + p];
      f32x4 vf = {bf2f(v4[0]), bf2f(v4[1]), bf2f(v4[2]), bf2f(v4[3])};
      #pragma unroll
      for (int s8 = 0; s8 < 8; ++s8) {
        float a = at[(sh * 8 + s8) * 16 + t];
        acc[s8] += a * vf;
      }
    }
    #pragma unroll
    for (int s8 = 0; s8 < 8; ++s8) {
      int s = sh * 8 + s8;
      *(f32x4*)&out[((size_t)(b * TD + s) * CDIM + c) * HWD + p] = acc[s8];
    }
  }
}

// ---------------- launch ----------------
extern "C" void kernel_launch(void* const* d_in, const int* in_sizes, int n_in,
                              void* d_out, int out_size, void* d_ws, size_t ws_size,
                              hipStream_t stream) {
  const float* x   = (const float*)d_in[0];
  const float* lnw = (const float*)d_in[1];
  const float* lnb = (const float*)d_in[2];
  const float* Wq  = (const float*)d_in[3];
  const float* Wk  = (const float*)d_in[4];
  const float* Wv  = (const float*)d_in[5];
  float* out = (float*)d_out;

  char* ws = (char*)d_ws;
  const size_t XNT_OFF   = 0;                       // bf16 [32][1024 q][1024 c]  64 MiB
  const size_t VP_OFF    = XNT_OFF + 67108864;      // bf16 [32][1024 c][1024 q]  64 MiB
  const size_t WB_OFF    = VP_OFF + 67108864;       // bf16 Wv                    2 MiB
  const size_t WQKB_OFF  = WB_OFF + 2097152;        // bf16 [Wq;Wk]               4 MiB
  const size_t POOLB_OFF = WQKB_OFF + 4194304;      // bf16 [32][1024]
  const size_t QM_OFF    = POOLB_OFF + 65536;
  const size_t KM_OFF    = QM_OFF + 131072;
  const size_t ATTN_OFF  = KM_OFF + 131072;         // f32 [32][16][16]

  short* xnT    = (short*)(ws + XNT_OFF);
  short* vp     = (short*)(ws + VP_OFF);
  // pool partials alias the vp region: written by k_ln, consumed by k_pool_red,
  // both strictly before k_vgemm writes vp (stream-ordered).
  float* part   = (float*)(ws + VP_OFF);            // f32 [32][16][1024] = 2 MiB
  short* Wb     = (short*)(ws + WB_OFF);
  short* Wqkb   = (short*)(ws + WQKB_OFF);
  short* poolb  = (short*)(ws + POOLB_OFF);
  float* qm     = (float*)(ws + QM_OFF);
  float* km     = (float*)(ws + KM_OFF);
  float* attn   = (float*)(ws + ATTN_OFF);

  k_cast3<<<dim3(3072), 256, 0, stream>>>(Wq, Wk, Wv, Wqkb, Wb);
  k_ln<<<dim3(16, 32), 512, 0, stream>>>(x, lnw, lnb, xnT, part);
  k_pool_red<<<dim3(4, 32), 256, 0, stream>>>(part, poolb);
  k_qk_mfma<<<dim3(16), 256, 0, stream>>>(Wqkb, poolb, qm, km);
  k_attn<<<dim3(32), 256, 0, stream>>>(qm, km, attn);
  k_vgemm<<<dim3(8, 8, 32), 256, 0, stream>>>(Wb, xnT, vp);
  k_mix<<<dim3(1024, 2), 256, 0, stream>>>(vp, attn, out);
}